// Round 15
// baseline (99.505 us; speedup 1.0000x reference)
//
#include <hip/hip_runtime.h>

// Fused no-softmax attention block, MI355X/gfx950.
// out = LN( q + Q @ Gt_b^T + bo ),  {Q,K,V} = {q,k,v}@W^T+b,
// Gt_b[n,k'] = sum_d M_bh[d',d]/8 * Wo[n,h*64+d],  M_bh = K^T V  (no softmax -> exact)
// R15 = R14 with kvfold re-tiled 64s x 128n (head-pair), BK=32, ring-3 36KB -> 4 blk/CU
// (R14 was 2 blk/CU at 72KB; per-CU LDS traffic & MFMA identical -> pure occupancy A/B).
// Pipeline: cvt_kvw -> fat_a3{kvfold64 || cvt q,Wq} -> fat_b2{proj_q || gt} -> out -> ln.

typedef __bf16 bf16;
typedef __bf16 bf16x4 __attribute__((ext_vector_type(4)));
typedef __bf16 bf16x8 __attribute__((ext_vector_type(8)));
typedef float f32x4 __attribute__((ext_vector_type(4)));

#define MFMA16(a, b, c) __builtin_amdgcn_mfma_f32_16x16x32_bf16(a, b, c, 0, 0, 0)
#define BARRIER() asm volatile("s_barrier" ::: "memory")
#define VMCNT4() asm volatile("s_waitcnt vmcnt(4)" ::: "memory")
#define VMCNT3() asm volatile("s_waitcnt vmcnt(3)" ::: "memory")
#define VMCNT0() asm volatile("s_waitcnt vmcnt(0)" ::: "memory")
#define LGKM0()                                        \
  do {                                                 \
    asm volatile("s_waitcnt lgkmcnt(0)" ::: "memory"); \
    __builtin_amdgcn_sched_barrier(0);                 \
  } while (0)

__device__ __forceinline__ bf16x8 ld8(const bf16* p) { return *(const bf16x8*)p; }

__device__ __forceinline__ void gload16(const void* g, void* l) {
  __builtin_amdgcn_global_load_lds((__attribute__((address_space(1))) void*)(g),
                                   (__attribute__((address_space(3))) void*)(l), 16, 0, 0);
}

__device__ __forceinline__ int swz4(int row) { return (row ^ (row >> 2)) & 3; }

__device__ __forceinline__ bf16x8 cvt8(f32x4 lo, f32x4 hi) {
  bf16x8 o;
  o[0] = (bf16)lo[0]; o[1] = (bf16)lo[1]; o[2] = (bf16)lo[2]; o[3] = (bf16)lo[3];
  o[4] = (bf16)hi[0]; o[5] = (bf16)hi[1]; o[6] = (bf16)hi[2]; o[7] = (bf16)hi[3];
  return o;
}

// ---------------- ring-3 bf16 GEMM loop 128x128, BK=32 (proj_q / gemm_out) ----------------
__device__ __forceinline__ void compute16(const char* buf, const int aoff[4], const int boff[4],
                                          f32x4 (&acc)[4][4]) {
  bf16x8 av[4], bv[4];
#pragma unroll
  for (int i = 0; i < 4; i++) av[i] = *(const bf16x8*)(buf + aoff[i]);
#pragma unroll
  for (int j = 0; j < 4; j++) bv[j] = *(const bf16x8*)(buf + boff[j]);
  __builtin_amdgcn_s_setprio(1);
#pragma unroll
  for (int i = 0; i < 4; i++)
#pragma unroll
    for (int j = 0; j < 4; j++) acc[i][j] = MFMA16(av[i], bv[j], acc[i][j]);
  __builtin_amdgcn_s_setprio(0);
}

__device__ __forceinline__ void ring128(const bf16* __restrict__ A, const bf16* __restrict__ B,
                                        char* lds, f32x4 (&acc)[4][4]) {
  const int t = threadIdx.x;
  const int lane = t & 63, wid = t >> 6;
  const int wr = wid >> 1, wc = wid & 1;
  const int r16 = lane & 15, kg = lane >> 4;

  int aoff[4], boff[4];
#pragma unroll
  for (int i = 0; i < 4; i++) {
    int row = wr * 64 + i * 16 + r16;
    aoff[i] = row * 64 + ((kg ^ swz4(row)) << 4);
    row = wc * 64 + i * 16 + r16;
    boff[i] = 8192 + row * 64 + ((kg ^ swz4(row)) << 4);
  }

  const int r1 = t >> 2, c = t & 3, r2 = r1 + 64;
  const bf16* pa1 = A + (size_t)r1 * 1024 + (c ^ swz4(r1)) * 8;
  const bf16* pa2 = A + (size_t)r2 * 1024 + (c ^ swz4(r2)) * 8;
  const bf16* pb1 = B + (size_t)r1 * 1024 + (c ^ swz4(r1)) * 8;
  const bf16* pb2 = B + (size_t)r2 * 1024 + (c ^ swz4(r2)) * 8;
  const int d1 = wid << 10, d2 = 4096 + (wid << 10);

#pragma unroll
  for (int p = 0; p < 2; p++) {
    char* d = lds + p * 16384;
    gload16(pa1 + p * 32, d + d1);
    gload16(pa2 + p * 32, d + d2);
    gload16(pb1 + p * 32, d + 8192 + d1);
    gload16(pb2 + p * 32, d + 8192 + d2);
  }
  pa1 += 64; pa2 += 64; pb1 += 64; pb2 += 64;

  int cb = 0, rb = 2;
  for (int kt = 0; kt < 30; kt++) {
    VMCNT4();
    BARRIER();
    {
      char* d = lds + rb * 16384;
      gload16(pa1, d + d1);
      gload16(pa2, d + d2);
      gload16(pb1, d + 8192 + d1);
      gload16(pb2, d + 8192 + d2);
      pa1 += 32; pa2 += 32; pb1 += 32; pb2 += 32;
    }
    compute16(lds + cb * 16384, aoff, boff, acc);
    LGKM0();
    cb = (cb == 2) ? 0 : cb + 1;
    rb = (rb == 2) ? 0 : rb + 1;
  }
  VMCNT4(); BARRIER();
  compute16(lds + cb * 16384, aoff, boff, acc);
  LGKM0();
  cb = (cb == 2) ? 0 : cb + 1;
  VMCNT0(); BARRIER();
  compute16(lds + cb * 16384, aoff, boff, acc);
}

__device__ __forceinline__ void proj_epi(f32x4 (&acc)[4][4], const float* bias,
                                         bf16* __restrict__ C, int m0, int n0) {
  const int lane = threadIdx.x & 63, wid = threadIdx.x >> 6;
  const int wr = wid >> 1, wc = wid & 1, r16 = lane & 15, kg = lane >> 4;
#pragma unroll
  for (int j = 0; j < 4; j++) {
    const int col = n0 + wc * 64 + j * 16 + r16;
    const float bj = bias[col];
#pragma unroll
    for (int i = 0; i < 4; i++) {
      const int row = m0 + wr * 64 + i * 16 + kg * 4;
#pragma unroll
      for (int r = 0; r < 4; r++)
        C[(size_t)(row + r) * 1024 + col] = (bf16)(acc[i][j][r] + bj);
    }
  }
}

// ---------------- ring-3 64x128 tile, BK=32 (kvfold): 4 blk/CU ----------------
// LDS buf: A[64][32] 4KB @0, B[128][32] 8KB @4096; buf stride 12288; x3 = 36864 B.
// 3 gloads/thread/tile (1 A + 2 B) -> VMCNT(3). 32 periods, wave tile 32x64 (2x4 frags).
__device__ __forceinline__ void ring64b(const bf16* __restrict__ A, const bf16* __restrict__ B,
                                        char* lds, f32x4 (&acc)[2][4]) {
  const int t = threadIdx.x;
  const int lane = t & 63, wid = t >> 6;
  const int wr = wid >> 1, wc = wid & 1;
  const int r16 = lane & 15, kg = lane >> 4;

  int aoff[2], boff[4];
#pragma unroll
  for (int i = 0; i < 2; i++) {
    const int row = wr * 32 + i * 16 + r16;
    aoff[i] = row * 64 + ((kg ^ swz4(row)) << 4);
  }
#pragma unroll
  for (int j = 0; j < 4; j++) {
    const int row = wc * 64 + j * 16 + r16;
    boff[j] = 4096 + row * 64 + ((kg ^ swz4(row)) << 4);
  }

  // staging: A slot t (row t>>2, chunk t&3); B slots t, t+256. Pre-swizzled source.
  const int ar = t >> 2, ac = t & 3;
  const bf16* pa = A + (size_t)ar * 1024 + (ac ^ swz4(ar)) * 8;
  const int adst = wid << 10;
  const bf16* pb[2]; int bdst[2];
#pragma unroll
  for (int p = 0; p < 2; p++) {
    const int slot = p * 256 + t;
    const int row = slot >> 2, c = slot & 3;
    pb[p] = B + (size_t)row * 1024 + (c ^ swz4(row)) * 8;
    bdst[p] = 4096 + p * 4096 + (wid << 10);
  }

  // prologue: tiles 0,1
#pragma unroll
  for (int kt0 = 0; kt0 < 2; kt0++) {
    char* d = lds + kt0 * 12288;
    gload16(pa + kt0 * 32, d + adst);
    gload16(pb[0] + kt0 * 32, d + bdst[0]);
    gload16(pb[1] + kt0 * 32, d + bdst[1]);
  }

  int cb = 0;
  for (int kt = 0; kt < 32; ++kt) {
    if (kt < 31) VMCNT3(); else VMCNT0();
    BARRIER();
    if (kt < 30) {
      char* d = lds + ((kt + 2) % 3) * 12288;
      gload16(pa + (kt + 2) * 32, d + adst);
      gload16(pb[0] + (kt + 2) * 32, d + bdst[0]);
      gload16(pb[1] + (kt + 2) * 32, d + bdst[1]);
    }
    const char* buf = lds + cb * 12288;
    bf16x8 av[2], bv[4];
#pragma unroll
    for (int i = 0; i < 2; i++) av[i] = *(const bf16x8*)(buf + aoff[i]);
#pragma unroll
    for (int j = 0; j < 4; j++) bv[j] = *(const bf16x8*)(buf + boff[j]);
    __builtin_amdgcn_s_setprio(1);
#pragma unroll
    for (int i = 0; i < 2; i++)
#pragma unroll
      for (int j = 0; j < 4; j++) acc[i][j] = MFMA16(av[i], bv[j], acc[i][j]);
    __builtin_amdgcn_s_setprio(0);
    LGKM0();
    cb = (cb == 2) ? 0 : cb + 1;
  }
}

// ---------------- 1. cvt_kvw: k,v (4096), Wk,Wv (1024), zero M (64) ----------------
__global__ __launch_bounds__(256) void cvt_kvw_kernel(
    const float* __restrict__ k, const float* __restrict__ v,
    const float* __restrict__ wk, const float* __restrict__ wv,
    bf16* __restrict__ kv_bf, bf16* __restrict__ wkv_bf, float* __restrict__ Mz) {
  const int bid = blockIdx.x;
  if (bid >= 5120) {
    float* p = Mz + (size_t)(bid - 5120) * 2048 + threadIdx.x * 8;
    *(f32x4*)p = f32x4{0.f, 0.f, 0.f, 0.f};
    *(f32x4*)(p + 4) = f32x4{0.f, 0.f, 0.f, 0.f};
    return;
  }
  const float* s; bf16* d; size_t dof; int x;
  if (bid < 4096) {
    const int y = bid >> 11; x = bid & 2047;
    s = (y == 0) ? k : v;
    d = kv_bf; dof = (size_t)y * 4194304u;
  } else {
    const int idx = bid - 4096; const int y = idx >> 9; x = idx & 511;
    s = (y == 0) ? wk : wv;
    d = wkv_bf; dof = (size_t)y * 1048576u;
  }
  const size_t i = ((size_t)x * 256 + threadIdx.x) * 8;
  *(bf16x8*)(d + dof + i) = cvt8(*(const f32x4*)(s + i), *(const f32x4*)(s + i + 4));
}

// ---------------- 2. fat_a3: kvfold64 (wg<512) || cvt q,Wq (wg>=512) ----------------
// kvfold block (mt,ntp): s-rows mt*64..+64, head-pair ntp (cols ntp*128..+128).
// K-pass, V-pass (ring64b, tiles in regs), then per head g in {0,1}: wave wc==g writes
// bias-added transpose into Kl/Vl [64][72], all waves fold 8 MFMA, atomicAdd into M.
__global__ __launch_bounds__(256, 4) void fat_a3_kernel(
    const bf16* __restrict__ kv_bf, const bf16* __restrict__ wkv,
    const float* __restrict__ bk, const float* __restrict__ bv_, float* __restrict__ Mout,
    const float* __restrict__ q, const float* __restrict__ wq,
    bf16* __restrict__ q_bf, bf16* __restrict__ wq_bf) {
  __shared__ __align__(1024) char lds[36864];
  const int wg = blockIdx.x;
  if (wg < 512) {
    const int swz = (wg & 7) * 64 + (wg >> 3);   // XCD-chunked, bijective (512%8==0)
    const int mt = swz >> 3, ntp = swz & 7;      // 64 s-slices x 8 head-pairs
    const int m0 = mt * 64;                      // global s-row (spans both batches)
    const int b = mt >> 5;

    f32x4 accK[2][4] = {}, accV[2][4] = {};
    ring64b(kv_bf + (size_t)m0 * 1024, wkv + (size_t)ntp * 131072u, lds, accK);
    __syncthreads();
    ring64b(kv_bf + 4194304u + (size_t)m0 * 1024, wkv + 1048576u + (size_t)ntp * 131072u,
            lds, accV);
    __syncthreads();

    bf16 (*Kl)[72] = (bf16(*)[72])lds;           // [d=64][s=64 pad 72]
    bf16 (*Vl)[72] = (bf16(*)[72])(lds + 9216);
    const int lane = threadIdx.x & 63, wid = threadIdx.x >> 6;
    const int wr = wid >> 1, wc = wid & 1, r16 = lane & 15, kg = lane >> 4;
#pragma unroll
    for (int g = 0; g < 2; ++g) {
      if (g) __syncthreads();  // round-0 fold reads done before overwrite
      if (wc == g) {           // this wave's acc cols = head g
#pragma unroll
        for (int j = 0; j < 4; j++) {
          const int dcol = j * 16 + r16;
          const int col = ntp * 128 + g * 64 + dcol;
          const float bkj = bk[col], bvj = bv_[col];
#pragma unroll
          for (int i = 0; i < 2; i++) {
            const int sb = wr * 32 + i * 16 + kg * 4;
            bf16x4 pk, pv;
#pragma unroll
            for (int r = 0; r < 4; r++) {
              pk[r] = (bf16)(accK[i][j][r] + bkj);
              pv[r] = (bf16)(accV[i][j][r] + bvj);
            }
            *(bf16x4*)&Kl[dcol][sb] = pk;
            *(bf16x4*)&Vl[dcol][sb] = pv;
          }
        }
      }
      __syncthreads();
      // fold: M_h[d',d] += sum_{s=0..63} Kl[d'][s] Vl[d][s]; wave wid owns d' wid*16..+16
      f32x4 accm[4] = {};
#pragma unroll
      for (int ks = 0; ks < 2; ks++) {
        bf16x8 a = ld8(&Kl[wid * 16 + r16][ks * 32 + kg * 8]);
#pragma unroll
        for (int j = 0; j < 4; j++) {
          bf16x8 bb = ld8(&Vl[j * 16 + r16][ks * 32 + kg * 8]);
          accm[j] = MFMA16(a, bb, accm[j]);
        }
      }
      float* Mh = Mout + (size_t)(b * 16 + ntp * 2 + g) * 4096;
#pragma unroll
      for (int j = 0; j < 4; j++)
#pragma unroll
        for (int r = 0; r < 4; r++)
          atomicAdd(&Mh[(wid * 16 + kg * 4 + r) * 64 + j * 16 + r16], accm[j][r]);
    }
    return;
  }
  // cvt side: q (2048 blk) + Wq (512 blk)
  const int idx = wg - 512;
  const float* s; bf16* d; int x;
  if (idx < 2048) { s = q; d = q_bf; x = idx; }
  else            { s = wq; d = wq_bf; x = idx - 2048; }
  const size_t i = ((size_t)x * 256 + threadIdx.x) * 8;
  *(bf16x8*)(d + i) = cvt8(*(const f32x4*)(s + i), *(const f32x4*)(s + i + 4));
}

// ---------------- 3. fat_b2: proj_q (wg<256) || gt (wg>=256) ----------------
__global__ __launch_bounds__(256, 3) void fat_b2_kernel(
    const bf16* __restrict__ q_bf, const bf16* __restrict__ wq_bf,
    const float* __restrict__ bq, bf16* __restrict__ Q_bf,
    const float* __restrict__ Wo, const float* __restrict__ M, bf16* __restrict__ Gt) {
  __shared__ __align__(1024) char lds[49152];
  const int wg = blockIdx.x;
  if (wg < 256) {  // Q = q @ Wq^T + bq
    const int swz = (wg & 7) * 32 + (wg >> 3);
    const int mt = swz >> 3, nt = swz & 7;
    const int m0 = mt * 128, n0 = nt * 128;
    f32x4 acc[4][4] = {};
    ring128(q_bf + (size_t)m0 * 1024, wq_bf + (size_t)n0 * 1024, lds, acc);
    proj_epi(acc, bq, Q_bf, m0, n0);
    return;
  }
  // gt: Gt[b][n][h*64+d'] = sum_d Wo[n,h*64+d](f32) * M_bh[d',d]/8
  const int bid = wg - 256;
  const int b = bid >> 7, h = (bid >> 3) & 15, nt = bid & 7;
  const int n0 = nt * 128;
  const float* Mh = M + (size_t)((b << 4) + h) * 4096;
  const int l = threadIdx.x & 63, w = threadIdx.x >> 6;
  const int r16 = l & 15, kg = l >> 4;
  f32x4 acc[2][4] = {};
#pragma unroll
  for (int kk = 0; kk < 2; kk++) {
    bf16x8 a[2];
#pragma unroll
    for (int i = 0; i < 2; i++) {
      const float* wp = Wo + (size_t)(n0 + w * 32 + i * 16 + r16) * 1024 + h * 64 + kk * 32 + kg * 8;
      a[i] = cvt8(*(const f32x4*)wp, *(const f32x4*)(wp + 4));
    }
#pragma unroll
    for (int j = 0; j < 4; j++) {
      const float* mp = Mh + (j * 16 + r16) * 64 + kk * 32 + kg * 8;
      f32x4 m0v = *(const f32x4*)mp;
      f32x4 m1v = *(const f32x4*)(mp + 4);
      f32x4 sl = {m0v[0] * 0.125f, m0v[1] * 0.125f, m0v[2] * 0.125f, m0v[3] * 0.125f};
      f32x4 sh = {m1v[0] * 0.125f, m1v[1] * 0.125f, m1v[2] * 0.125f, m1v[3] * 0.125f};
      bf16x8 bv = cvt8(sl, sh);
#pragma unroll
      for (int i = 0; i < 2; i++) acc[i][j] = MFMA16(a[i], bv, acc[i][j]);
    }
  }
  bf16* G = Gt + (size_t)b * 1048576u;
#pragma unroll
  for (int i = 0; i < 2; i++)
#pragma unroll
    for (int j = 0; j < 4; j++)
#pragma unroll
      for (int r = 0; r < 4; r++)
        G[(size_t)(n0 + w * 32 + i * 16 + kg * 4 + r) * 1024 + h * 64 + j * 16 + r16] =
            (bf16)acc[i][j][r];
}

// ---------------- 4. x = resid + Q @ Gt_b^T + bo  -> bf16 ws ----------------
__global__ __launch_bounds__(256, 3) void gemm_out_r(
    const bf16* __restrict__ Q, const bf16* __restrict__ Gt,
    const float* __restrict__ bo, const float* __restrict__ resid, bf16* __restrict__ xb) {
  __shared__ __align__(1024) char lds[49152];
  const int wg = blockIdx.x;
  const int swz = (wg & 7) * 32 + (wg >> 3);
  const int mt = swz >> 3, nt = swz & 7;
  const int m0 = mt * 128, n0 = nt * 128;

  f32x4 acc[4][4] = {};
  ring128(Q + (size_t)m0 * 1024, Gt + (size_t)(m0 >> 11) * 1048576u + (size_t)n0 * 1024, lds, acc);

  const int lane = threadIdx.x & 63, wid = threadIdx.x >> 6;
  const int wr = wid >> 1, wc = wid & 1, r16 = lane & 15, kg = lane >> 4;
#pragma unroll
  for (int j = 0; j < 4; j++) {
    const int col = n0 + wc * 64 + j * 16 + r16;
    const float bj = bo[col];
#pragma unroll
    for (int i = 0; i < 4; i++) {
      const int row = m0 + wr * 64 + i * 16 + kg * 4;
#pragma unroll
      for (int r = 0; r < 4; r++) {
        const size_t off = (size_t)(row + r) * 1024 + col;
        xb[off] = (bf16)(acc[i][j][r] + bj + resid[off]);
      }
    }
  }
}

// ---------------- 5. LayerNorm: x bf16 -> out f32, one row per wave ----------------
__global__ __launch_bounds__(256) void ln_kernel(
    const bf16* __restrict__ xb, const float* __restrict__ g, const float* __restrict__ bb,
    float* __restrict__ out) {
  const int lane = threadIdx.x & 63, wid = threadIdx.x >> 6;
  const int row = (blockIdx.x << 2) + wid;
  const bf16* xr = xb + (size_t)row * 1024;
  bf16x8 h0 = ld8(xr + lane * 16);
  bf16x8 h1 = ld8(xr + lane * 16 + 8);
  float v[16];
#pragma unroll
  for (int e = 0; e < 8; e++) { v[e] = (float)h0[e]; v[8 + e] = (float)h1[e]; }
  float s = 0.f, s2 = 0.f;
#pragma unroll
  for (int e = 0; e < 16; e++) { s += v[e]; s2 += v[e] * v[e]; }
#pragma unroll
  for (int m = 32; m; m >>= 1) { s += __shfl_xor(s, m); s2 += __shfl_xor(s2, m); }
  const float mu = s * (1.0f / 1024.0f);
  const float rstd = rsqrtf(s2 * (1.0f / 1024.0f) - mu * mu + 1e-5f);
  float* orow = out + (size_t)row * 1024 + lane * 16;
#pragma unroll
  for (int e = 0; e < 4; e++) {
    f32x4 gg = *(const f32x4*)(g + lane * 16 + e * 4);
    f32x4 bv = *(const f32x4*)(bb + lane * 16 + e * 4);
    f32x4 o;
#pragma unroll
    for (int u = 0; u < 4; u++) o[u] = gg[u] * ((v[e * 4 + u] - mu) * rstd) + bv[u];
    *(f32x4*)(orow + e * 4) = o;
  }
}

extern "C" void kernel_launch(void* const* d_in, const int* in_sizes, int n_in,
                              void* d_out, int out_size, void* d_ws, size_t ws_size,
                              hipStream_t stream) {
  (void)in_sizes; (void)n_in; (void)out_size; (void)ws_size;
  const float* q    = (const float*)d_in[0];
  const float* k    = (const float*)d_in[1];
  const float* v    = (const float*)d_in[2];
  // d_in[3]=mask (all False), d_in[4]=training: unused
  const float* wq_w = (const float*)d_in[5];
  const float* wq_b = (const float*)d_in[6];
  const float* wk_w = (const float*)d_in[7];
  const float* wk_b = (const float*)d_in[8];
  const float* wv_w = (const float*)d_in[9];
  const float* wv_b = (const float*)d_in[10];
  const float* wo_w = (const float*)d_in[11];
  const float* wo_b = (const float*)d_in[12];
  const float* ln_g = (const float*)d_in[13];
  const float* ln_b = (const float*)d_in[14];
  float* out = (float*)d_out;

  bf16* wsb    = (bf16*)d_ws;
  bf16* q_bf   = wsb;                        // [0, 4M)
  bf16* kv_bf  = wsb + 4194304u;             // [4M, 12M): k_bf, v_bf
  bf16* w_bf   = wsb + 12582912u;            // Wq (12M), Wk (13M), Wv (14M)
  bf16* Q_bf   = wsb + 15728640u;            // [15M, 19M)
  bf16* Gt     = wsb + 19922944u;            // 2,097,152 elems
  bf16* xb     = wsb + 22020096u;            // 4,194,304 elems
  float* M     = (float*)(wsb + 28311552u);  // 131072 f32 (zeroed in cvt_kvw)

  cvt_kvw_kernel<<<5184, 256, 0, stream>>>(k, v, wk_w, wv_w, kv_bf, w_bf + 1048576u, M);
  fat_a3_kernel<<<3072, 256, 0, stream>>>(kv_bf, w_bf + 1048576u, wk_b, wv_b, M,
                                          q, wq_w, q_bf, w_bf);
  fat_b2_kernel<<<512, 256, 0, stream>>>(q_bf, w_bf, wq_b, Q_bf, wo_w, M, Gt);
  gemm_out_r<<<256, 256, 0, stream>>>(Q_bf, Gt, wo_b, q, xb);
  ln_kernel<<<1024, 256, 0, stream>>>(xb, ln_g, ln_b, out);
}

// Round 16
// 85.826 us; speedup vs baseline: 1.1594x; 1.1594x over previous
//
#include <hip/hip_runtime.h>

// Fused no-softmax attention block, MI355X/gfx950.
// out = LN( q + Q @ Gt_b^T + bo ),  {Q,K,V} = {q,k,v}@W^T+b,
// Gt_b[n,k'] = sum_d M_bh[d',d]/8 * Wo[n,h*64+d],  M_bh = K^T V  (no softmax -> exact)
// R16 = R14 verbatim (measured best, 86.1us). R15's retiling regressed (bank conflicts
// 295K->3.4M + shallower prefetch); R14 is the local optimum: 128x64 head-tile, BK=64,
// ring-3 72KB, conflict-free 8-chunk swizzle, VMCNT(6), K/V never hit HBM.
// Pipeline: cvt_kvw -> fat_a2{kvfold || cvt q,Wq} -> fat_b2{proj_q || gt} -> out -> ln.

typedef __bf16 bf16;
typedef __bf16 bf16x4 __attribute__((ext_vector_type(4)));
typedef __bf16 bf16x8 __attribute__((ext_vector_type(8)));
typedef float f32x4 __attribute__((ext_vector_type(4)));

#define MFMA16(a, b, c) __builtin_amdgcn_mfma_f32_16x16x32_bf16(a, b, c, 0, 0, 0)
#define BARRIER() asm volatile("s_barrier" ::: "memory")
#define VMCNT6() asm volatile("s_waitcnt vmcnt(6)" ::: "memory")
#define VMCNT4() asm volatile("s_waitcnt vmcnt(4)" ::: "memory")
#define VMCNT0() asm volatile("s_waitcnt vmcnt(0)" ::: "memory")
#define LGKM0()                                        \
  do {                                                 \
    asm volatile("s_waitcnt lgkmcnt(0)" ::: "memory"); \
    __builtin_amdgcn_sched_barrier(0);                 \
  } while (0)

__device__ __forceinline__ bf16x8 ld8(const bf16* p) { return *(const bf16x8*)p; }

__device__ __forceinline__ void gload16(const void* g, void* l) {
  __builtin_amdgcn_global_load_lds((__attribute__((address_space(1))) void*)(g),
                                   (__attribute__((address_space(3))) void*)(l), 16, 0, 0);
}

__device__ __forceinline__ int swz4(int row) { return (row ^ (row >> 2)) & 3; }

__device__ __forceinline__ bf16x8 cvt8(f32x4 lo, f32x4 hi) {
  bf16x8 o;
  o[0] = (bf16)lo[0]; o[1] = (bf16)lo[1]; o[2] = (bf16)lo[2]; o[3] = (bf16)lo[3];
  o[4] = (bf16)hi[0]; o[5] = (bf16)hi[1]; o[6] = (bf16)hi[2]; o[7] = (bf16)hi[3];
  return o;
}

// ---------------- ring-3 bf16 GEMM loop 128x128, BK=32 (proj_q / gemm_out) ----------------
__device__ __forceinline__ void compute16(const char* buf, const int aoff[4], const int boff[4],
                                          f32x4 (&acc)[4][4]) {
  bf16x8 av[4], bv[4];
#pragma unroll
  for (int i = 0; i < 4; i++) av[i] = *(const bf16x8*)(buf + aoff[i]);
#pragma unroll
  for (int j = 0; j < 4; j++) bv[j] = *(const bf16x8*)(buf + boff[j]);
  __builtin_amdgcn_s_setprio(1);
#pragma unroll
  for (int i = 0; i < 4; i++)
#pragma unroll
    for (int j = 0; j < 4; j++) acc[i][j] = MFMA16(av[i], bv[j], acc[i][j]);
  __builtin_amdgcn_s_setprio(0);
}

__device__ __forceinline__ void ring128(const bf16* __restrict__ A, const bf16* __restrict__ B,
                                        char* lds, f32x4 (&acc)[4][4]) {
  const int t = threadIdx.x;
  const int lane = t & 63, wid = t >> 6;
  const int wr = wid >> 1, wc = wid & 1;
  const int r16 = lane & 15, kg = lane >> 4;

  int aoff[4], boff[4];
#pragma unroll
  for (int i = 0; i < 4; i++) {
    int row = wr * 64 + i * 16 + r16;
    aoff[i] = row * 64 + ((kg ^ swz4(row)) << 4);
    row = wc * 64 + i * 16 + r16;
    boff[i] = 8192 + row * 64 + ((kg ^ swz4(row)) << 4);
  }

  const int r1 = t >> 2, c = t & 3, r2 = r1 + 64;
  const bf16* pa1 = A + (size_t)r1 * 1024 + (c ^ swz4(r1)) * 8;
  const bf16* pa2 = A + (size_t)r2 * 1024 + (c ^ swz4(r2)) * 8;
  const bf16* pb1 = B + (size_t)r1 * 1024 + (c ^ swz4(r1)) * 8;
  const bf16* pb2 = B + (size_t)r2 * 1024 + (c ^ swz4(r2)) * 8;
  const int d1 = wid << 10, d2 = 4096 + (wid << 10);

#pragma unroll
  for (int p = 0; p < 2; p++) {
    char* d = lds + p * 16384;
    gload16(pa1 + p * 32, d + d1);
    gload16(pa2 + p * 32, d + d2);
    gload16(pb1 + p * 32, d + 8192 + d1);
    gload16(pb2 + p * 32, d + 8192 + d2);
  }
  pa1 += 64; pa2 += 64; pb1 += 64; pb2 += 64;

  int cb = 0, rb = 2;
  for (int kt = 0; kt < 30; kt++) {
    VMCNT4();
    BARRIER();
    {
      char* d = lds + rb * 16384;
      gload16(pa1, d + d1);
      gload16(pa2, d + d2);
      gload16(pb1, d + 8192 + d1);
      gload16(pb2, d + 8192 + d2);
      pa1 += 32; pa2 += 32; pb1 += 32; pb2 += 32;
    }
    compute16(lds + cb * 16384, aoff, boff, acc);
    LGKM0();
    cb = (cb == 2) ? 0 : cb + 1;
    rb = (rb == 2) ? 0 : rb + 1;
  }
  VMCNT4(); BARRIER();
  compute16(lds + cb * 16384, aoff, boff, acc);
  LGKM0();
  cb = (cb == 2) ? 0 : cb + 1;
  VMCNT0(); BARRIER();
  compute16(lds + cb * 16384, aoff, boff, acc);
}

__device__ __forceinline__ void proj_epi(f32x4 (&acc)[4][4], const float* bias,
                                         bf16* __restrict__ C, int m0, int n0) {
  const int lane = threadIdx.x & 63, wid = threadIdx.x >> 6;
  const int wr = wid >> 1, wc = wid & 1, r16 = lane & 15, kg = lane >> 4;
#pragma unroll
  for (int j = 0; j < 4; j++) {
    const int col = n0 + wc * 64 + j * 16 + r16;
    const float bj = bias[col];
#pragma unroll
    for (int i = 0; i < 4; i++) {
      const int row = m0 + wr * 64 + i * 16 + kg * 4;
#pragma unroll
      for (int r = 0; r < 4; r++)
        C[(size_t)(row + r) * 1024 + col] = (bf16)(acc[i][j][r] + bj);
    }
  }
}

// ---------------- ring-3 128x64 tile, BK=64 (KV-proj+fold): 16 MFMA/period, 16 periods ----
// LDS buf = A[128][64] 16KB + B[64][64] 8KB = 24KB; ring-3 = 73728 B.
// 8-chunk swizzle: chunk slot = c ^ (row&7). 6 gloads/thread/tile -> VMCNT(6).
__device__ __forceinline__ void ring64(const bf16* __restrict__ A, const bf16* __restrict__ B,
                                       char* lds, f32x4 (&acc)[4][2]) {
  const int t = threadIdx.x;
  const int lane = t & 63, wid = t >> 6;
  const int wr = wid >> 1, wc = wid & 1;
  const int r16 = lane & 15, kg = lane >> 4;

  int aoff[4][2], boff[2][2];
#pragma unroll
  for (int i = 0; i < 4; i++) {
    const int row = wr * 64 + i * 16 + r16;
#pragma unroll
    for (int kk = 0; kk < 2; kk++)
      aoff[i][kk] = row * 128 + (((kk * 4 + kg) ^ (row & 7)) << 4);
  }
#pragma unroll
  for (int j = 0; j < 2; j++) {
    const int row = wc * 32 + j * 16 + r16;
#pragma unroll
    for (int kk = 0; kk < 2; kk++)
      boff[j][kk] = 16384 + row * 128 + (((kk * 4 + kg) ^ (row & 7)) << 4);
  }

  // staging: A 1024 slots (4/thread), B 512 slots (2/thread); pre-swizzled source
  const bf16* pa[4]; const bf16* pb[2];
  int adst[4], bdst[2];
#pragma unroll
  for (int p = 0; p < 4; p++) {
    const int slot = p * 256 + t;
    const int row = slot >> 3, c = slot & 7;
    pa[p] = A + (size_t)row * 1024 + (c ^ (row & 7)) * 8;
    adst[p] = p * 4096 + (wid << 10);
  }
#pragma unroll
  for (int p = 0; p < 2; p++) {
    const int slot = p * 256 + t;
    const int row = slot >> 3, c = slot & 7;
    pb[p] = B + (size_t)row * 1024 + (c ^ (row & 7)) * 8;
    bdst[p] = 16384 + p * 4096 + (wid << 10);
  }

  // prologue: tiles 0,1 (6 gloads each per thread)
#pragma unroll
  for (int kt0 = 0; kt0 < 2; kt0++) {
    char* d = lds + kt0 * 24576;
#pragma unroll
    for (int p = 0; p < 4; p++) gload16(pa[p] + kt0 * 64, d + adst[p]);
#pragma unroll
    for (int p = 0; p < 2; p++) gload16(pb[p] + kt0 * 64, d + bdst[p]);
  }

  int cb = 0;
  for (int kt = 0; kt < 16; ++kt) {
    if (kt < 14) VMCNT6(); else if (kt == 14) VMCNT6(); else VMCNT0();
    BARRIER();
    if (kt < 14) {
      char* d = lds + ((kt + 2) % 3) * 24576;
#pragma unroll
      for (int p = 0; p < 4; p++) gload16(pa[p] + (kt + 2) * 64, d + adst[p]);
#pragma unroll
      for (int p = 0; p < 2; p++) gload16(pb[p] + (kt + 2) * 64, d + bdst[p]);
    }
    const char* buf = lds + cb * 24576;
#pragma unroll
    for (int kk = 0; kk < 2; kk++) {
      bf16x8 av[4], bv[2];
#pragma unroll
      for (int i = 0; i < 4; i++) av[i] = *(const bf16x8*)(buf + aoff[i][kk]);
#pragma unroll
      for (int j = 0; j < 2; j++) bv[j] = *(const bf16x8*)(buf + boff[j][kk]);
      __builtin_amdgcn_s_setprio(1);
#pragma unroll
      for (int i = 0; i < 4; i++)
#pragma unroll
        for (int j = 0; j < 2; j++) acc[i][j] = MFMA16(av[i], bv[j], acc[i][j]);
      __builtin_amdgcn_s_setprio(0);
    }
    LGKM0();
    cb = (cb == 2) ? 0 : cb + 1;
  }
}

// ---------------- 1. cvt_kvw: k,v (4096), Wk,Wv (1024), zero M (64) ----------------
__global__ __launch_bounds__(256) void cvt_kvw_kernel(
    const float* __restrict__ k, const float* __restrict__ v,
    const float* __restrict__ wk, const float* __restrict__ wv,
    bf16* __restrict__ kv_bf, bf16* __restrict__ wkv_bf, float* __restrict__ Mz) {
  const int bid = blockIdx.x;
  if (bid >= 5120) {
    float* p = Mz + (size_t)(bid - 5120) * 2048 + threadIdx.x * 8;
    *(f32x4*)p = f32x4{0.f, 0.f, 0.f, 0.f};
    *(f32x4*)(p + 4) = f32x4{0.f, 0.f, 0.f, 0.f};
    return;
  }
  const float* s; bf16* d; size_t dof; int x;
  if (bid < 4096) {
    const int y = bid >> 11; x = bid & 2047;
    s = (y == 0) ? k : v;
    d = kv_bf; dof = (size_t)y * 4194304u;
  } else {
    const int idx = bid - 4096; const int y = idx >> 9; x = idx & 511;
    s = (y == 0) ? wk : wv;
    d = wkv_bf; dof = (size_t)y * 1048576u;
  }
  const size_t i = ((size_t)x * 256 + threadIdx.x) * 8;
  *(bf16x8*)(d + dof + i) = cvt8(*(const f32x4*)(s + i), *(const f32x4*)(s + i + 4));
}

// ---------------- 2. fat_a2: KV-proj+fold (wg<512) || cvt q,Wq (wg>=512) ----------------
// kvfold block (mt,nt): s-rows mt*128..+128, head h=nt (cols h*64..+64). K-pass, V-pass
// (tiles in regs), then fold M_h += K^T V via LDS transpose + 16 MFMA/wave + atomicAdd.
__global__ __launch_bounds__(256, 2) void fat_a2_kernel(
    const bf16* __restrict__ kv_bf, const bf16* __restrict__ wkv,
    const float* __restrict__ bk, const float* __restrict__ bv_, float* __restrict__ Mout,
    const float* __restrict__ q, const float* __restrict__ wq,
    bf16* __restrict__ q_bf, bf16* __restrict__ wq_bf) {
  __shared__ __align__(1024) char lds[73728];
  const int wg = blockIdx.x;
  if (wg < 512) {
    const int swz = (wg & 7) * 64 + (wg >> 3);   // XCD-chunked, bijective (512%8==0)
    const int mt = swz >> 4, nt = swz & 15;      // 32 m-slices x 16 heads
    const int m0 = mt * 128;                     // global s-row (spans both batches)
    const int b = mt >> 4;

    f32x4 accK[4][2] = {}, accV[4][2] = {};
    ring64(kv_bf + (size_t)m0 * 1024, wkv + (size_t)nt * 64 * 1024, lds, accK);
    __syncthreads();
    ring64(kv_bf + 4194304u + (size_t)m0 * 1024, wkv + 1048576u + (size_t)nt * 64 * 1024,
           lds, accV);
    __syncthreads();

    bf16 (*Kl)[136] = (bf16(*)[136])lds;           // [d=64][s=128 pad 136]
    bf16 (*Vl)[136] = (bf16(*)[136])(lds + 17408);
    const int lane = threadIdx.x & 63, wid = threadIdx.x >> 6;
    const int wr = wid >> 1, wc = wid & 1, r16 = lane & 15, kg = lane >> 4;
#pragma unroll
    for (int j = 0; j < 2; j++) {
      const int d = wc * 32 + j * 16 + r16;
      const int col = nt * 64 + d;
      const float bkj = bk[col], bvj = bv_[col];
#pragma unroll
      for (int i = 0; i < 4; i++) {
        const int sb = wr * 64 + i * 16 + kg * 4;
        bf16x4 pk, pv;
#pragma unroll
        for (int r = 0; r < 4; r++) {
          pk[r] = (bf16)(accK[i][j][r] + bkj);
          pv[r] = (bf16)(accV[i][j][r] + bvj);
        }
        *(bf16x4*)&Kl[d][sb] = pk;
        *(bf16x4*)&Vl[d][sb] = pv;
      }
    }
    __syncthreads();
    // fold: M_h[d',d] += sum_{s=0..127} Kl[d'][s] * Vl[d][s]; wave wid owns rows wid*16..+16
    f32x4 accm[4] = {};
#pragma unroll
    for (int ks = 0; ks < 4; ks++) {
      bf16x8 a = ld8(&Kl[wid * 16 + r16][ks * 32 + kg * 8]);
#pragma unroll
      for (int j = 0; j < 4; j++) {
        bf16x8 bb = ld8(&Vl[j * 16 + r16][ks * 32 + kg * 8]);
        accm[j] = MFMA16(a, bb, accm[j]);
      }
    }
    float* Mh = Mout + (size_t)(b * 16 + nt) * 4096;
#pragma unroll
    for (int j = 0; j < 4; j++)
#pragma unroll
      for (int r = 0; r < 4; r++)
        atomicAdd(&Mh[(wid * 16 + kg * 4 + r) * 64 + j * 16 + r16], accm[j][r]);
    return;
  }
  // cvt side: q (2048 blk) + Wq (512 blk)
  const int idx = wg - 512;
  const float* s; bf16* d; int x;
  if (idx < 2048) { s = q; d = q_bf; x = idx; }
  else            { s = wq; d = wq_bf; x = idx - 2048; }
  const size_t i = ((size_t)x * 256 + threadIdx.x) * 8;
  *(bf16x8*)(d + i) = cvt8(*(const f32x4*)(s + i), *(const f32x4*)(s + i + 4));
}

// ---------------- 3. fat_b2: proj_q (wg<256) || gt (wg>=256) ----------------
__global__ __launch_bounds__(256, 3) void fat_b2_kernel(
    const bf16* __restrict__ q_bf, const bf16* __restrict__ wq_bf,
    const float* __restrict__ bq, bf16* __restrict__ Q_bf,
    const float* __restrict__ Wo, const float* __restrict__ M, bf16* __restrict__ Gt) {
  __shared__ __align__(1024) char lds[49152];
  const int wg = blockIdx.x;
  if (wg < 256) {  // Q = q @ Wq^T + bq
    const int swz = (wg & 7) * 32 + (wg >> 3);
    const int mt = swz >> 3, nt = swz & 7;
    const int m0 = mt * 128, n0 = nt * 128;
    f32x4 acc[4][4] = {};
    ring128(q_bf + (size_t)m0 * 1024, wq_bf + (size_t)n0 * 1024, lds, acc);
    proj_epi(acc, bq, Q_bf, m0, n0);
    return;
  }
  // gt: Gt[b][n][h*64+d'] = sum_d Wo[n,h*64+d](f32) * M_bh[d',d]/8
  const int bid = wg - 256;
  const int b = bid >> 7, h = (bid >> 3) & 15, nt = bid & 7;
  const int n0 = nt * 128;
  const float* Mh = M + (size_t)((b << 4) + h) * 4096;
  const int l = threadIdx.x & 63, w = threadIdx.x >> 6;
  const int r16 = l & 15, kg = l >> 4;
  f32x4 acc[2][4] = {};
#pragma unroll
  for (int kk = 0; kk < 2; kk++) {
    bf16x8 a[2];
#pragma unroll
    for (int i = 0; i < 2; i++) {
      const float* wp = Wo + (size_t)(n0 + w * 32 + i * 16 + r16) * 1024 + h * 64 + kk * 32 + kg * 8;
      a[i] = cvt8(*(const f32x4*)wp, *(const f32x4*)(wp + 4));
    }
#pragma unroll
    for (int j = 0; j < 4; j++) {
      const float* mp = Mh + (j * 16 + r16) * 64 + kk * 32 + kg * 8;
      f32x4 m0v = *(const f32x4*)mp;
      f32x4 m1v = *(const f32x4*)(mp + 4);
      f32x4 sl = {m0v[0] * 0.125f, m0v[1] * 0.125f, m0v[2] * 0.125f, m0v[3] * 0.125f};
      f32x4 sh = {m1v[0] * 0.125f, m1v[1] * 0.125f, m1v[2] * 0.125f, m1v[3] * 0.125f};
      bf16x8 bv = cvt8(sl, sh);
#pragma unroll
      for (int i = 0; i < 2; i++) acc[i][j] = MFMA16(a[i], bv, acc[i][j]);
    }
  }
  bf16* G = Gt + (size_t)b * 1048576u;
#pragma unroll
  for (int i = 0; i < 2; i++)
#pragma unroll
    for (int j = 0; j < 4; j++)
#pragma unroll
      for (int r = 0; r < 4; r++)
        G[(size_t)(n0 + w * 32 + i * 16 + kg * 4 + r) * 1024 + h * 64 + j * 16 + r16] =
            (bf16)acc[i][j][r];
}

// ---------------- 4. x = resid + Q @ Gt_b^T + bo  -> bf16 ws ----------------
__global__ __launch_bounds__(256, 3) void gemm_out_r(
    const bf16* __restrict__ Q, const bf16* __restrict__ Gt,
    const float* __restrict__ bo, const float* __restrict__ resid, bf16* __restrict__ xb) {
  __shared__ __align__(1024) char lds[49152];
  const int wg = blockIdx.x;
  const int swz = (wg & 7) * 32 + (wg >> 3);
  const int mt = swz >> 3, nt = swz & 7;
  const int m0 = mt * 128, n0 = nt * 128;

  f32x4 acc[4][4] = {};
  ring128(Q + (size_t)m0 * 1024, Gt + (size_t)(m0 >> 11) * 1048576u + (size_t)n0 * 1024, lds, acc);

  const int lane = threadIdx.x & 63, wid = threadIdx.x >> 6;
  const int wr = wid >> 1, wc = wid & 1, r16 = lane & 15, kg = lane >> 4;
#pragma unroll
  for (int j = 0; j < 4; j++) {
    const int col = n0 + wc * 64 + j * 16 + r16;
    const float bj = bo[col];
#pragma unroll
    for (int i = 0; i < 4; i++) {
      const int row = m0 + wr * 64 + i * 16 + kg * 4;
#pragma unroll
      for (int r = 0; r < 4; r++) {
        const size_t off = (size_t)(row + r) * 1024 + col;
        xb[off] = (bf16)(acc[i][j][r] + bj + resid[off]);
      }
    }
  }
}

// ---------------- 5. LayerNorm: x bf16 -> out f32, one row per wave ----------------
__global__ __launch_bounds__(256) void ln_kernel(
    const bf16* __restrict__ xb, const float* __restrict__ g, const float* __restrict__ bb,
    float* __restrict__ out) {
  const int lane = threadIdx.x & 63, wid = threadIdx.x >> 6;
  const int row = (blockIdx.x << 2) + wid;
  const bf16* xr = xb + (size_t)row * 1024;
  bf16x8 h0 = ld8(xr + lane * 16);
  bf16x8 h1 = ld8(xr + lane * 16 + 8);
  float v[16];
#pragma unroll
  for (int e = 0; e < 8; e++) { v[e] = (float)h0[e]; v[8 + e] = (float)h1[e]; }
  float s = 0.f, s2 = 0.f;
#pragma unroll
  for (int e = 0; e < 16; e++) { s += v[e]; s2 += v[e] * v[e]; }
#pragma unroll
  for (int m = 32; m; m >>= 1) { s += __shfl_xor(s, m); s2 += __shfl_xor(s2, m); }
  const float mu = s * (1.0f / 1024.0f);
  const float rstd = rsqrtf(s2 * (1.0f / 1024.0f) - mu * mu + 1e-5f);
  float* orow = out + (size_t)row * 1024 + lane * 16;
#pragma unroll
  for (int e = 0; e < 4; e++) {
    f32x4 gg = *(const f32x4*)(g + lane * 16 + e * 4);
    f32x4 bv = *(const f32x4*)(bb + lane * 16 + e * 4);
    f32x4 o;
#pragma unroll
    for (int u = 0; u < 4; u++) o[u] = gg[u] * ((v[e * 4 + u] - mu) * rstd) + bv[u];
    *(f32x4*)(orow + e * 4) = o;
  }
}

extern "C" void kernel_launch(void* const* d_in, const int* in_sizes, int n_in,
                              void* d_out, int out_size, void* d_ws, size_t ws_size,
                              hipStream_t stream) {
  (void)in_sizes; (void)n_in; (void)out_size; (void)ws_size;
  const float* q    = (const float*)d_in[0];
  const float* k    = (const float*)d_in[1];
  const float* v    = (const float*)d_in[2];
  // d_in[3]=mask (all False), d_in[4]=training: unused
  const float* wq_w = (const float*)d_in[5];
  const float* wq_b = (const float*)d_in[6];
  const float* wk_w = (const float*)d_in[7];
  const float* wk_b = (const float*)d_in[8];
  const float* wv_w = (const float*)d_in[9];
  const float* wv_b = (const float*)d_in[10];
  const float* wo_w = (const float*)d_in[11];
  const float* wo_b = (const float*)d_in[12];
  const float* ln_g = (const float*)d_in[13];
  const float* ln_b = (const float*)d_in[14];
  float* out = (float*)d_out;

  bf16* wsb    = (bf16*)d_ws;
  bf16* q_bf   = wsb;                        // [0, 4M)
  bf16* kv_bf  = wsb + 4194304u;             // [4M, 12M): k_bf, v_bf
  bf16* w_bf   = wsb + 12582912u;            // Wq (12M), Wk (13M), Wv (14M)
  bf16* Q_bf   = wsb + 15728640u;            // [15M, 19M)
  bf16* Gt     = wsb + 19922944u;            // 2,097,152 elems
  bf16* xb     = wsb + 22020096u;            // 4,194,304 elems
  float* M     = (float*)(wsb + 28311552u);  // 131072 f32 (zeroed in cvt_kvw)

  cvt_kvw_kernel<<<5184, 256, 0, stream>>>(k, v, wk_w, wv_w, kv_bf, w_bf + 1048576u, M);
  fat_a2_kernel<<<3072, 256, 0, stream>>>(kv_bf, w_bf + 1048576u, wk_b, wv_b, M,
                                          q, wq_w, q_bf, w_bf);
  fat_b2_kernel<<<512, 256, 0, stream>>>(q_bf, w_bf, wq_b, Q_bf, wo_w, M, Gt);
  gemm_out_r<<<256, 256, 0, stream>>>(Q_bf, Gt, wo_b, q, xb);
  ln_kernel<<<1024, 256, 0, stream>>>(xb, ln_g, ln_b, out);
}